// Round 6
// baseline (420.478 us; speedup 1.0000x reference)
//
#include <hip/hip_runtime.h>
#include <math.h>
#include <stdint.h>

// MoE: B=8192 tokens, D_IN=1024, 8 experts, D_EXP=1024, top-2.
// Pipeline: fused prep (conflict-free w-transpose + x-cast + fp64 gating + init)
// -> single-block slot assign -> gathered bf16 MFMA GEMMs (A via LDS swizzle,
// B direct from global/L2) -> weighted combine.

#define NTOK   8192
#define DIN    1024
#define NEXP   8
#define DEXP   1024
#define MAXROWS 17408   // 16384 assignments + per-expert pad to 128 (= 17*1024)
#define MAXTILES 136

typedef __bf16 bf16x8_t __attribute__((ext_vector_type(8)));
typedef float f32x4 __attribute__((ext_vector_type(4)));

__device__ __forceinline__ unsigned short f2bf(float f) {
  union { float f; unsigned int u; } v; v.f = f;
  unsigned int u = v.u;
  u += 0x7fffu + ((u >> 16) & 1u);   // round-to-nearest-even
  return (unsigned short)(u >> 16);
}

__device__ __forceinline__ float bf2f(unsigned short s) {
  union { unsigned int u; float f; } v; v.u = ((unsigned int)s) << 16;
  return v.f;
}

__device__ __forceinline__ void async16(const void* g, void* l) {
  __builtin_amdgcn_global_load_lds((const __attribute__((address_space(1))) void*)g,
                                   (__attribute__((address_space(3))) void*)l, 16, 0, 0);
}

// fast GELU: tanh form via sigmoid, max abs err ~3e-4 (threshold is 5.7e-2)
__device__ __forceinline__ float gelu_fast(float v) {
  float u = v * (1.5957691216057308f + 0.07135481627f * v * v);
  return v * (1.0f / (1.0f + __expf(-u)));
}

// ---------------- fused prep: [0,4096) w-transpose | [4096,6144) x-cast+gate | [6144,6161) rowTok init
__global__ __launch_bounds__(256) void prep_kernel(const float* __restrict__ x,
                                                   const float* __restrict__ gw,
                                                   const float* __restrict__ w1,
                                                   const float* __restrict__ w2,
                                                   unsigned short* __restrict__ xbf,
                                                   unsigned short* __restrict__ w1T,
                                                   unsigned short* __restrict__ w2T,
                                                   float* __restrict__ outGate,
                                                   int* __restrict__ topE,
                                                   float* __restrict__ topW,
                                                   int* __restrict__ rowTok) {
  // lds[n][k], stride 65 (=1 mod 32): all scalar accesses below are 2-way == free
  __shared__ float lds[64 * 65];
  int b = blockIdx.x;
  int tid = threadIdx.x;
  if (b < 4096) {
    // ---- weight transpose+cast: [e][k][n] fp32 -> [e][n][k] bf16, 64x64 tile
    int z = b >> 8;                        // 0..15
    const float* src = (z < 8) ? w1 : w2;
    unsigned short* dst = (z < 8) ? w1T : w2T;
    int e = z & 7;
    int idx = b & 255, kt = idx >> 4, nt = idx & 15;
    const float* s = src + (size_t)e * DIN * DEXP + (size_t)kt * 64 * 1024 + nt * 64;
    unsigned short* d = dst + (size_t)e * DIN * DEXP + (size_t)nt * 64 * 1024 + kt * 64;
    int c4 = (tid & 15) * 4, r0 = tid >> 4;
    #pragma unroll
    for (int p = 0; p < 4; ++p) {
      int r = r0 + p * 16;
      float4 v = *(const float4*)(s + (size_t)r * 1024 + c4);
      lds[(c4 + 0) * 65 + r] = v.x;
      lds[(c4 + 1) * 65 + r] = v.y;
      lds[(c4 + 2) * 65 + r] = v.z;
      lds[(c4 + 3) * 65 + r] = v.w;
    }
    __syncthreads();
    int nr = tid >> 2, ksb = (tid & 3) * 16;
    #pragma unroll
    for (int m = 0; m < 2; ++m) {
      unsigned int o[4];
      #pragma unroll
      for (int i = 0; i < 4; ++i) {
        unsigned int lo = f2bf(lds[nr * 65 + ksb + m * 8 + i * 2]);
        unsigned int hi = f2bf(lds[nr * 65 + ksb + m * 8 + i * 2 + 1]);
        o[i] = lo | (hi << 16);
      }
      *(uint4*)(d + (size_t)nr * 1024 + ksb + m * 8) = *(uint4*)o;
    }
  } else if (b < 6144) {
    // ---- x fp32->bf16 + fp64 gating (one wave per token)
    int lane = tid & 63, wv = tid >> 6;
    int t = (b - 4096) * 4 + wv;
    const float4* xr = (const float4*)(x + (size_t)t * 1024);
    ushort4* xo = (ushort4*)(xbf + (size_t)t * 1024);
    double acc[NEXP];
    #pragma unroll
    for (int e = 0; e < NEXP; ++e) acc[e] = 0.0;
    #pragma unroll
    for (int j = 0; j < 4; ++j) {
      int q = lane + 64 * j;
      float4 v = xr[q];
      ushort4 r;
      r.x = f2bf(v.x); r.y = f2bf(v.y); r.z = f2bf(v.z); r.w = f2bf(v.w);
      xo[q] = r;
      float vv[4] = {v.x, v.y, v.z, v.w};
      #pragma unroll
      for (int m = 0; m < 4; ++m) {
        int k = q * 4 + m;
        float4 g0 = *(const float4*)(gw + k * 8);
        float4 g1 = *(const float4*)(gw + k * 8 + 4);
        double xv = (double)vv[m];
        acc[0] += xv * (double)g0.x; acc[1] += xv * (double)g0.y;
        acc[2] += xv * (double)g0.z; acc[3] += xv * (double)g0.w;
        acc[4] += xv * (double)g1.x; acc[5] += xv * (double)g1.y;
        acc[6] += xv * (double)g1.z; acc[7] += xv * (double)g1.w;
      }
    }
    #pragma unroll
    for (int off = 32; off > 0; off >>= 1) {
      #pragma unroll
      for (int e = 0; e < NEXP; ++e) acc[e] += __shfl_xor(acc[e], off);
    }
    if (lane == 0) {
      int e0 = 0; double v0 = acc[0];
      #pragma unroll
      for (int e = 1; e < NEXP; ++e) if (acc[e] > v0) { v0 = acc[e]; e0 = e; }
      int e1 = -1; double v1 = -1e300;
      #pragma unroll
      for (int e = 0; e < NEXP; ++e) if (e != e0 && acc[e] > v1) { v1 = acc[e]; e1 = e; }
      float ex = expf((float)(v1 - v0));
      float inv = 1.0f / (1.0f + ex);
      float w0 = inv, w1v = ex * inv;
      float g8[8];
      #pragma unroll
      for (int e = 0; e < NEXP; ++e) g8[e] = 0.f;
      g8[e0] = w0; g8[e1] = w1v;
      float4* gp = (float4*)(outGate + t * 8);
      gp[0] = *(float4*)&g8[0];
      gp[1] = *(float4*)&g8[4];
      topE[t * 2 + 0] = e0; topE[t * 2 + 1] = e1;
      topW[t * 2 + 0] = w0; topW[t * 2 + 1] = w1v;
    }
  } else {
    // ---- rowTok = -1 (17 blocks x 1024 ints)
    int base = (b - 6144) * 1024 + tid * 4;
    int4 m1 = make_int4(-1, -1, -1, -1);
    *(int4*)(rowTok + base) = m1;
  }
}

// ---------------- slots, tile table, topRow, rowTok scatter: one block ----------------
__global__ __launch_bounds__(1024) void slot_kernel(const int* __restrict__ topE,
                                                    int* __restrict__ topRow,
                                                    int* __restrict__ rowTok,
                                                    int* __restrict__ tileExpert,
                                                    int* __restrict__ tileRowBase) {
  __shared__ int wtot[16][NEXP];
  __shared__ int wbase[16][NEXP];
  __shared__ int soff[NEXP];
  int tid = threadIdx.x, lane = tid & 63, wv = tid >> 6;
  int a0 = tid * 16;
  unsigned long long pk = 0ull;
  int cnt[NEXP];
  #pragma unroll
  for (int e = 0; e < NEXP; ++e) cnt[e] = 0;
  for (int i = 0; i < 16; ++i) {
    int e = topE[a0 + i];
    pk |= (unsigned long long)e << (i * 4);
    cnt[e]++;
  }
  int excl[NEXP];
  #pragma unroll
  for (int e = 0; e < NEXP; ++e) {
    int v = cnt[e], sum = v;
    #pragma unroll
    for (int d = 1; d < 64; d <<= 1) {
      int u = __shfl_up(sum, d);
      if (lane >= d) sum += u;
    }
    excl[e] = sum - v;
    if (lane == 63) wtot[wv][e] = sum;
  }
  __syncthreads();
  if (tid == 0) {
    int counts[NEXP];
    for (int e = 0; e < NEXP; ++e) {
      int s = 0;
      for (int w = 0; w < 16; ++w) { wbase[w][e] = s; s += wtot[w][e]; }
      counts[e] = s;
    }
    int row = 0, tile = 0;
    for (int e = 0; e < NEXP; ++e) {
      soff[e] = row;
      int nt = (counts[e] + 127) >> 7;
      for (int i = 0; i < nt; ++i) { tileExpert[tile] = e; tileRowBase[tile] = row + i * 128; ++tile; }
      row += nt << 7;
    }
    for (; tile < MAXTILES; ++tile) tileExpert[tile] = -1;
  }
  __syncthreads();
  int base[NEXP], run[NEXP];
  #pragma unroll
  for (int e = 0; e < NEXP; ++e) { base[e] = soff[e] + wbase[wv][e] + excl[e]; run[e] = 0; }
  for (int i = 0; i < 16; ++i) {
    int e = (int)((pk >> (i * 4)) & 7ull);
    int row = base[e] + run[e]++;
    rowTok[row] = (a0 + i) >> 1;
    topRow[a0 + i] = row;
  }
}

// ---------------- GEMM1: h = gelu(Xg @ W1[e] + b1[e]), bf16 out ----------------
// A (gathered tokens) staged in LDS via global_load_lds + XOR k-chunk swizzle;
// B (weights, L2-resident) read directly global->VGPR fragments.
__global__ __launch_bounds__(256) void gemm1_kernel(const unsigned short* __restrict__ xbf,
                                                    const unsigned short* __restrict__ w1T,
                                                    const float* __restrict__ b1,
                                                    const int* __restrict__ tileExpert,
                                                    const int* __restrict__ tileRowBase,
                                                    const int* __restrict__ rowTok,
                                                    unsigned short* __restrict__ h) {
  int tileId = blockIdx.x;
  int e = tileExpert[tileId];
  if (e < 0) return;
  int rowBase = tileRowBase[tileId];
  int n0 = blockIdx.y * 128;
  __shared__ __align__(16) unsigned short sm[128 * 128];  // 32KB; first 16KB = A staging
  int tid = threadIdx.x, lane = tid & 63, wv = tid >> 6;
  int srow = tid >> 3;                       // 0..31 (+32 per issue)
  int scolSw = (((tid & 7) ^ ((tid >> 3) & 7)) * 8);   // swizzled k-chunk fetch
  int tok[4];
  #pragma unroll
  for (int i = 0; i < 4; ++i) {
    int tk = rowTok[rowBase + srow + i * 32];
    tok[i] = tk < 0 ? 0 : tk;
  }
  int wm = ((tid >> 6) & 1) * 64, wn = (tid >> 7) * 64;
  int rsel = lane & 15, q = lane >> 4, q8 = q * 8;
  int rk = rsel & 7;
  const unsigned short* Brow[4];
  #pragma unroll
  for (int ni = 0; ni < 4; ++ni)
    Brow[ni] = w1T + (size_t)e * DIN * DEXP + (size_t)(n0 + wn + ni * 16 + rsel) * 1024 + q8;
  f32x4 acc[4][4] = {};
  for (int kk = 0; kk < DIN; kk += 64) {
    #pragma unroll
    for (int i = 0; i < 4; ++i) {
      int abase = __builtin_amdgcn_readfirstlane((wv * 8 + i * 32) * 128);
      async16(xbf + (size_t)tok[i] * 1024 + kk + scolSw, (char*)sm + abase);
    }
    bf16x8_t bfr[2][4];
    #pragma unroll
    for (int ks2 = 0; ks2 < 2; ++ks2)
      #pragma unroll
      for (int ni = 0; ni < 4; ++ni)
        bfr[ks2][ni] = *(const bf16x8_t*)(Brow[ni] + kk + ks2 * 32);
    __syncthreads();
    #pragma unroll
    for (int ks2 = 0; ks2 < 2; ++ks2) {
      int co = (((ks2 * 4) + q) ^ rk) * 8;   // swizzled element offset in A row
      bf16x8_t af[4];
      #pragma unroll
      for (int mi = 0; mi < 4; ++mi)
        af[mi] = *(const bf16x8_t*)&sm[(wm + mi * 16 + rsel) * 64 + co];
      #pragma unroll
      for (int mi = 0; mi < 4; ++mi)
        #pragma unroll
        for (int ni = 0; ni < 4; ++ni)
          acc[mi][ni] = __builtin_amdgcn_mfma_f32_16x16x32_bf16(af[mi], bfr[ks2][ni], acc[mi][ni], 0, 0, 0);
    }
    __syncthreads();
  }
  float b1v[4];
  int quad = lane >> 4;
  #pragma unroll
  for (int ni = 0; ni < 4; ++ni) b1v[ni] = b1[e * 1024 + n0 + wn + ni * 16 + rsel];
  #pragma unroll
  for (int mi = 0; mi < 4; ++mi)
    #pragma unroll
    for (int ni = 0; ni < 4; ++ni)
      #pragma unroll
      for (int r = 0; r < 4; ++r) {
        int m = wm + mi * 16 + quad * 4 + r;
        int n = wn + ni * 16 + rsel;
        sm[m * 128 + n] = f2bf(gelu_fast(acc[mi][ni][r] + b1v[ni]));
      }
  __syncthreads();
  #pragma unroll
  for (int i = 0; i < 8; ++i) {
    int idx = i * 2048 + tid * 8;
    int m = idx >> 7, c = idx & 127;
    int g = rowBase + m;
    *(uint4*)(h + (size_t)g * 1024 + n0 + c) = *(const uint4*)&sm[idx];
  }
}

// ---------------- GEMM2: y[row] = h[row] @ W2[e] + b2[e] (bf16) ----------------
__global__ __launch_bounds__(256) void gemm2_kernel(const unsigned short* __restrict__ h,
                                                    const unsigned short* __restrict__ w2T,
                                                    const float* __restrict__ b2,
                                                    const int* __restrict__ tileExpert,
                                                    const int* __restrict__ tileRowBase,
                                                    unsigned short* __restrict__ y) {
  int tileId = blockIdx.x;
  int e = tileExpert[tileId];
  if (e < 0) return;
  int rowBase = tileRowBase[tileId];
  int n0 = blockIdx.y * 128;
  __shared__ __align__(16) unsigned short sm[128 * 128];
  int tid = threadIdx.x, lane = tid & 63, wv = tid >> 6;
  int srow = tid >> 3;
  int scolSw = (((tid & 7) ^ ((tid >> 3) & 7)) * 8);
  int wm = ((tid >> 6) & 1) * 64, wn = (tid >> 7) * 64;
  int rsel = lane & 15, q = lane >> 4, q8 = q * 8;
  int rk = rsel & 7;
  const unsigned short* Brow[4];
  #pragma unroll
  for (int ni = 0; ni < 4; ++ni)
    Brow[ni] = w2T + (size_t)e * DEXP * DEXP + (size_t)(n0 + wn + ni * 16 + rsel) * 1024 + q8;
  f32x4 acc[4][4] = {};
  for (int kk = 0; kk < DEXP; kk += 64) {
    #pragma unroll
    for (int i = 0; i < 4; ++i) {
      int abase = __builtin_amdgcn_readfirstlane((wv * 8 + i * 32) * 128);
      async16(h + (size_t)(rowBase + srow + i * 32) * 1024 + kk + scolSw, (char*)sm + abase);
    }
    bf16x8_t bfr[2][4];
    #pragma unroll
    for (int ks2 = 0; ks2 < 2; ++ks2)
      #pragma unroll
      for (int ni = 0; ni < 4; ++ni)
        bfr[ks2][ni] = *(const bf16x8_t*)(Brow[ni] + kk + ks2 * 32);
    __syncthreads();
    #pragma unroll
    for (int ks2 = 0; ks2 < 2; ++ks2) {
      int co = (((ks2 * 4) + q) ^ rk) * 8;
      bf16x8_t af[4];
      #pragma unroll
      for (int mi = 0; mi < 4; ++mi)
        af[mi] = *(const bf16x8_t*)&sm[(wm + mi * 16 + rsel) * 64 + co];
      #pragma unroll
      for (int mi = 0; mi < 4; ++mi)
        #pragma unroll
        for (int ni = 0; ni < 4; ++ni)
          acc[mi][ni] = __builtin_amdgcn_mfma_f32_16x16x32_bf16(af[mi], bfr[ks2][ni], acc[mi][ni], 0, 0, 0);
    }
    __syncthreads();
  }
  float b2v[4];
  int quad = lane >> 4;
  #pragma unroll
  for (int ni = 0; ni < 4; ++ni) b2v[ni] = b2[e * 1024 + n0 + wn + ni * 16 + rsel];
  #pragma unroll
  for (int mi = 0; mi < 4; ++mi)
    #pragma unroll
    for (int ni = 0; ni < 4; ++ni)
      #pragma unroll
      for (int r = 0; r < 4; ++r) {
        int m = wm + mi * 16 + quad * 4 + r;
        int n = wn + ni * 16 + rsel;
        sm[m * 128 + n] = f2bf(acc[mi][ni][r] + b2v[ni]);
      }
  __syncthreads();
  #pragma unroll
  for (int i = 0; i < 8; ++i) {
    int idx = i * 2048 + tid * 8;
    int m = idx >> 7, c = idx & 127;
    int g = rowBase + m;
    *(uint4*)(y + (size_t)g * 1024 + n0 + c) = *(const uint4*)&sm[idx];
  }
}

// ---------------- combine: out[t] = w0*y[r0] + w1*y[r1] ----------------
__global__ __launch_bounds__(256) void combine_kernel(const unsigned short* __restrict__ y,
                                                      const int* __restrict__ topRow,
                                                      const float* __restrict__ topW,
                                                      float* __restrict__ out) {
  int tid = threadIdx.x;
  int wv = tid >> 6, lane = tid & 63;
  int t = blockIdx.x * 4 + wv;
  int r0 = topRow[t * 2 + 0], r1 = topRow[t * 2 + 1];
  float w0 = topW[t * 2 + 0], w1 = topW[t * 2 + 1];
  const unsigned short* p0 = y + (size_t)r0 * 1024 + lane * 16;
  const unsigned short* p1 = y + (size_t)r1 * 1024 + lane * 16;
  float* op = out + (size_t)t * 1024 + lane * 16;
  #pragma unroll
  for (int hh = 0; hh < 2; ++hh) {
    union { uint4 v; unsigned short s[8]; } a, b;
    a.v = *(const uint4*)(p0 + hh * 8);
    b.v = *(const uint4*)(p1 + hh * 8);
    float o[8];
    #pragma unroll
    for (int j = 0; j < 8; ++j)
      o[j] = w0 * bf2f(a.s[j]) + w1 * bf2f(b.s[j]);
    *(float4*)(op + hh * 8) = *(float4*)&o[0];
    *(float4*)(op + hh * 8 + 4) = *(float4*)&o[4];
  }
}

extern "C" void kernel_launch(void* const* d_in, const int* in_sizes, int n_in,
                              void* d_out, int out_size, void* d_ws, size_t ws_size,
                              hipStream_t stream) {
  const float* x  = (const float*)d_in[0];
  const float* gw = (const float*)d_in[1];
  const float* w1 = (const float*)d_in[2];
  const float* b1 = (const float*)d_in[3];
  const float* w2 = (const float*)d_in[4];
  const float* b2 = (const float*)d_in[5];
  float* out = (float*)d_out;

  char* ws = (char*)d_ws;
  int* tileExpert  = (int*)ws;                            // 136
  int* tileRowBase = tileExpert + MAXTILES;               // 136
  int* topE        = tileRowBase + MAXTILES;              // 16384
  int* topRow      = topE + 16384;                        // 16384
  float* topW      = (float*)(topRow + 16384);            // 16384
  int* rowTok      = (int*)(ws + (256 << 10));            // 17408 (16B aligned)
  unsigned short* xbf  = (unsigned short*)(ws + (512 << 10));
  unsigned short* w1T  = xbf + (size_t)NTOK * DIN;
  unsigned short* w2T  = w1T + (size_t)NEXP * DIN * DEXP;
  unsigned short* hbuf = w2T + (size_t)NEXP * DEXP * DEXP;
  unsigned short* ybuf = hbuf + (size_t)MAXROWS * DEXP;

  prep_kernel<<<4096 + 2048 + 17, 256, 0, stream>>>(x, gw, w1, w2, xbf, w1T, w2T,
                                                    out + (size_t)NTOK * DEXP,
                                                    topE, topW, rowTok);
  slot_kernel<<<1, 1024, 0, stream>>>(topE, topRow, rowTok, tileExpert, tileRowBase);
  gemm1_kernel<<<dim3(MAXTILES, 8), 256, 0, stream>>>(xbf, w1T, b1, tileExpert, tileRowBase,
                                                      rowTok, hbuf);
  gemm2_kernel<<<dim3(MAXTILES, 8), 256, 0, stream>>>(hbuf, w2T, b2, tileExpert, tileRowBase,
                                                      ybuf);
  combine_kernel<<<NTOK / 4, 256, 0, stream>>>(ybuf, topRow, topW, out);
}

// Round 7
// 334.190 us; speedup vs baseline: 1.2582x; 1.2582x over previous
//
#include <hip/hip_runtime.h>
#include <math.h>
#include <stdint.h>

// MoE: B=8192 tokens, D_IN=1024, 8 experts, D_EXP=1024, top-2.
// Pipeline: fused prep (conflict-free w-transpose + x-cast + fp64 gating + init)
// -> single-block slot assign -> gathered bf16 MFMA GEMMs (A+B staged in LDS
// via global_load_lds, XOR-swizzled reads) -> weighted combine.
// R6 lesson: B must stay LDS-staged (block-level broadcast + coalescing);
// direct-from-global B regressed 1.5x.

#define NTOK   8192
#define DIN    1024
#define NEXP   8
#define DEXP   1024
#define MAXROWS 17408   // 16384 assignments + per-expert pad to 128 (= 17*1024)
#define MAXTILES 136

typedef __bf16 bf16x8_t __attribute__((ext_vector_type(8)));
typedef float f32x4 __attribute__((ext_vector_type(4)));

__device__ __forceinline__ unsigned short f2bf(float f) {
  union { float f; unsigned int u; } v; v.f = f;
  unsigned int u = v.u;
  u += 0x7fffu + ((u >> 16) & 1u);   // round-to-nearest-even
  return (unsigned short)(u >> 16);
}

__device__ __forceinline__ float bf2f(unsigned short s) {
  union { unsigned int u; float f; } v; v.u = ((unsigned int)s) << 16;
  return v.f;
}

__device__ __forceinline__ void async16(const void* g, void* l) {
  __builtin_amdgcn_global_load_lds((const __attribute__((address_space(1))) void*)g,
                                   (__attribute__((address_space(3))) void*)l, 16, 0, 0);
}

// fast GELU: tanh form via sigmoid, max abs err ~3e-4 (threshold is 5.7e-2)
__device__ __forceinline__ float gelu_fast(float v) {
  float u = v * (1.5957691216057308f + 0.07135481627f * v * v);
  return v * (1.0f / (1.0f + __expf(-u)));
}

// ---------------- fused prep: [0,4096) w-transpose | [4096,6144) x-cast+gate | [6144,6161) rowTok init
__global__ __launch_bounds__(256) void prep_kernel(const float* __restrict__ x,
                                                   const float* __restrict__ gw,
                                                   const float* __restrict__ w1,
                                                   const float* __restrict__ w2,
                                                   unsigned short* __restrict__ xbf,
                                                   unsigned short* __restrict__ w1T,
                                                   unsigned short* __restrict__ w2T,
                                                   float* __restrict__ outGate,
                                                   int* __restrict__ topE,
                                                   float* __restrict__ topW,
                                                   int* __restrict__ rowTok) {
  // lds[n][k], stride 65 (=1 mod 32): all scalar accesses below are 2-way == free
  __shared__ float lds[64 * 65];
  int b = blockIdx.x;
  int tid = threadIdx.x;
  if (b < 4096) {
    // ---- weight transpose+cast: [e][k][n] fp32 -> [e][n][k] bf16, 64x64 tile
    int z = b >> 8;                        // 0..15
    const float* src = (z < 8) ? w1 : w2;
    unsigned short* dst = (z < 8) ? w1T : w2T;
    int e = z & 7;
    int idx = b & 255, kt = idx >> 4, nt = idx & 15;
    const float* s = src + (size_t)e * DIN * DEXP + (size_t)kt * 64 * 1024 + nt * 64;
    unsigned short* d = dst + (size_t)e * DIN * DEXP + (size_t)nt * 64 * 1024 + kt * 64;
    int c4 = (tid & 15) * 4, r0 = tid >> 4;
    #pragma unroll
    for (int p = 0; p < 4; ++p) {
      int r = r0 + p * 16;
      float4 v = *(const float4*)(s + (size_t)r * 1024 + c4);
      lds[(c4 + 0) * 65 + r] = v.x;
      lds[(c4 + 1) * 65 + r] = v.y;
      lds[(c4 + 2) * 65 + r] = v.z;
      lds[(c4 + 3) * 65 + r] = v.w;
    }
    __syncthreads();
    int nr = tid >> 2, ksb = (tid & 3) * 16;
    #pragma unroll
    for (int m = 0; m < 2; ++m) {
      unsigned int o[4];
      #pragma unroll
      for (int i = 0; i < 4; ++i) {
        unsigned int lo = f2bf(lds[nr * 65 + ksb + m * 8 + i * 2]);
        unsigned int hi = f2bf(lds[nr * 65 + ksb + m * 8 + i * 2 + 1]);
        o[i] = lo | (hi << 16);
      }
      *(uint4*)(d + (size_t)nr * 1024 + ksb + m * 8) = *(uint4*)o;
    }
  } else if (b < 6144) {
    // ---- x fp32->bf16 + fp64 gating (one wave per token)
    int lane = tid & 63, wv = tid >> 6;
    int t = (b - 4096) * 4 + wv;
    const float4* xr = (const float4*)(x + (size_t)t * 1024);
    ushort4* xo = (ushort4*)(xbf + (size_t)t * 1024);
    double acc[NEXP];
    #pragma unroll
    for (int e = 0; e < NEXP; ++e) acc[e] = 0.0;
    #pragma unroll
    for (int j = 0; j < 4; ++j) {
      int q = lane + 64 * j;
      float4 v = xr[q];
      ushort4 r;
      r.x = f2bf(v.x); r.y = f2bf(v.y); r.z = f2bf(v.z); r.w = f2bf(v.w);
      xo[q] = r;
      float vv[4] = {v.x, v.y, v.z, v.w};
      #pragma unroll
      for (int m = 0; m < 4; ++m) {
        int k = q * 4 + m;
        float4 g0 = *(const float4*)(gw + k * 8);
        float4 g1 = *(const float4*)(gw + k * 8 + 4);
        double xv = (double)vv[m];
        acc[0] += xv * (double)g0.x; acc[1] += xv * (double)g0.y;
        acc[2] += xv * (double)g0.z; acc[3] += xv * (double)g0.w;
        acc[4] += xv * (double)g1.x; acc[5] += xv * (double)g1.y;
        acc[6] += xv * (double)g1.z; acc[7] += xv * (double)g1.w;
      }
    }
    #pragma unroll
    for (int off = 32; off > 0; off >>= 1) {
      #pragma unroll
      for (int e = 0; e < NEXP; ++e) acc[e] += __shfl_xor(acc[e], off);
    }
    if (lane == 0) {
      int e0 = 0; double v0 = acc[0];
      #pragma unroll
      for (int e = 1; e < NEXP; ++e) if (acc[e] > v0) { v0 = acc[e]; e0 = e; }
      int e1 = -1; double v1 = -1e300;
      #pragma unroll
      for (int e = 0; e < NEXP; ++e) if (e != e0 && acc[e] > v1) { v1 = acc[e]; e1 = e; }
      float ex = expf((float)(v1 - v0));
      float inv = 1.0f / (1.0f + ex);
      float w0 = inv, w1v = ex * inv;
      float g8[8];
      #pragma unroll
      for (int e = 0; e < NEXP; ++e) g8[e] = 0.f;
      g8[e0] = w0; g8[e1] = w1v;
      float4* gp = (float4*)(outGate + t * 8);
      gp[0] = *(float4*)&g8[0];
      gp[1] = *(float4*)&g8[4];
      topE[t * 2 + 0] = e0; topE[t * 2 + 1] = e1;
      topW[t * 2 + 0] = w0; topW[t * 2 + 1] = w1v;
    }
  } else {
    // ---- rowTok = -1 (17 blocks x 1024 ints)
    int base = (b - 6144) * 1024 + tid * 4;
    int4 m1 = make_int4(-1, -1, -1, -1);
    *(int4*)(rowTok + base) = m1;
  }
}

// ---------------- slots, tile table, topRow, rowTok scatter: one block ----------------
__global__ __launch_bounds__(1024) void slot_kernel(const int* __restrict__ topE,
                                                    int* __restrict__ topRow,
                                                    int* __restrict__ rowTok,
                                                    int* __restrict__ tileExpert,
                                                    int* __restrict__ tileRowBase) {
  __shared__ int wtot[16][NEXP];
  __shared__ int wbase[16][NEXP];
  __shared__ int soff[NEXP];
  int tid = threadIdx.x, lane = tid & 63, wv = tid >> 6;
  int a0 = tid * 16;
  unsigned long long pk = 0ull;
  int cnt[NEXP];
  #pragma unroll
  for (int e = 0; e < NEXP; ++e) cnt[e] = 0;
  for (int i = 0; i < 16; ++i) {
    int e = topE[a0 + i];
    pk |= (unsigned long long)e << (i * 4);
    cnt[e]++;
  }
  int excl[NEXP];
  #pragma unroll
  for (int e = 0; e < NEXP; ++e) {
    int v = cnt[e], sum = v;
    #pragma unroll
    for (int d = 1; d < 64; d <<= 1) {
      int u = __shfl_up(sum, d);
      if (lane >= d) sum += u;
    }
    excl[e] = sum - v;
    if (lane == 63) wtot[wv][e] = sum;
  }
  __syncthreads();
  if (tid == 0) {
    int counts[NEXP];
    for (int e = 0; e < NEXP; ++e) {
      int s = 0;
      for (int w = 0; w < 16; ++w) { wbase[w][e] = s; s += wtot[w][e]; }
      counts[e] = s;
    }
    int row = 0, tile = 0;
    for (int e = 0; e < NEXP; ++e) {
      soff[e] = row;
      int nt = (counts[e] + 127) >> 7;
      for (int i = 0; i < nt; ++i) { tileExpert[tile] = e; tileRowBase[tile] = row + i * 128; ++tile; }
      row += nt << 7;
    }
    for (; tile < MAXTILES; ++tile) tileExpert[tile] = -1;
  }
  __syncthreads();
  int base[NEXP], run[NEXP];
  #pragma unroll
  for (int e = 0; e < NEXP; ++e) { base[e] = soff[e] + wbase[wv][e] + excl[e]; run[e] = 0; }
  for (int i = 0; i < 16; ++i) {
    int e = (int)((pk >> (i * 4)) & 7ull);
    int row = base[e] + run[e]++;
    rowTok[row] = (a0 + i) >> 1;
    topRow[a0 + i] = row;
  }
}

// ---------------- GEMM1: h = gelu(Xg @ W1[e] + b1[e]), bf16 out ----------------
// A+B staged in LDS via global_load_lds with XOR k-chunk swizzle.
__global__ __launch_bounds__(256) void gemm1_kernel(const unsigned short* __restrict__ xbf,
                                                    const unsigned short* __restrict__ w1T,
                                                    const float* __restrict__ b1,
                                                    const int* __restrict__ tileExpert,
                                                    const int* __restrict__ tileRowBase,
                                                    const int* __restrict__ rowTok,
                                                    unsigned short* __restrict__ h) {
  int tileId = blockIdx.x;
  int e = tileExpert[tileId];
  if (e < 0) return;
  int rowBase = tileRowBase[tileId];
  int n0 = blockIdx.y * 128;
  __shared__ __align__(16) unsigned short sm[128 * 64 * 2];  // 32KB: sA | sB
  unsigned short* sA = sm;
  unsigned short* sB = sm + 128 * 64;
  int tid = threadIdx.x, lane = tid & 63, wv = tid >> 6;
  int srow = tid >> 3;                       // 0..31 (+32 per issue)
  int scolSw = (((tid & 7) ^ ((tid >> 3) & 7)) * 8);   // swizzled k-chunk fetch
  int tok[4];
  #pragma unroll
  for (int i = 0; i < 4; ++i) {
    int tk = rowTok[rowBase + srow + i * 32];
    tok[i] = tk < 0 ? 0 : tk;
  }
  const unsigned short* Bmat = w1T + (size_t)e * DIN * DEXP;
  int wm = ((tid >> 6) & 1) * 64, wn = (tid >> 7) * 64;
  int rsel = lane & 15, q = lane >> 4;
  int rk = rsel & 7;
  f32x4 acc[4][4] = {};
  for (int kk = 0; kk < DIN; kk += 64) {
    #pragma unroll
    for (int i = 0; i < 4; ++i) {
      int abase = __builtin_amdgcn_readfirstlane((wv * 8 + i * 32) * 128);
      async16(xbf + (size_t)tok[i] * 1024 + kk + scolSw, (char*)sm + abase);
      async16(Bmat + (size_t)(n0 + srow + i * 32) * 1024 + kk + scolSw,
              (char*)sm + abase + 16384);
    }
    __syncthreads();
    #pragma unroll
    for (int ks2 = 0; ks2 < 2; ++ks2) {
      int co = ((ks2 * 4 + q) ^ rk) * 8;   // swizzled element offset in row
      bf16x8_t af[4], bfr[4];
      #pragma unroll
      for (int mi = 0; mi < 4; ++mi)
        af[mi] = *(const bf16x8_t*)&sA[(wm + mi * 16 + rsel) * 64 + co];
      #pragma unroll
      for (int ni = 0; ni < 4; ++ni)
        bfr[ni] = *(const bf16x8_t*)&sB[(wn + ni * 16 + rsel) * 64 + co];
      #pragma unroll
      for (int mi = 0; mi < 4; ++mi)
        #pragma unroll
        for (int ni = 0; ni < 4; ++ni)
          acc[mi][ni] = __builtin_amdgcn_mfma_f32_16x16x32_bf16(af[mi], bfr[ni], acc[mi][ni], 0, 0, 0);
    }
    __syncthreads();
  }
  float b1v[4];
  int quad = lane >> 4;
  #pragma unroll
  for (int ni = 0; ni < 4; ++ni) b1v[ni] = b1[e * 1024 + n0 + wn + ni * 16 + rsel];
  #pragma unroll
  for (int mi = 0; mi < 4; ++mi)
    #pragma unroll
    for (int ni = 0; ni < 4; ++ni)
      #pragma unroll
      for (int r = 0; r < 4; ++r) {
        int m = wm + mi * 16 + quad * 4 + r;
        int n = wn + ni * 16 + rsel;
        sm[m * 128 + n] = f2bf(gelu_fast(acc[mi][ni][r] + b1v[ni]));
      }
  __syncthreads();
  #pragma unroll
  for (int i = 0; i < 8; ++i) {
    int idx = i * 2048 + tid * 8;
    int m = idx >> 7, c = idx & 127;
    int g = rowBase + m;
    *(uint4*)(h + (size_t)g * 1024 + n0 + c) = *(const uint4*)&sm[idx];
  }
}

// ---------------- GEMM2: y[row] = h[row] @ W2[e] + b2[e] (bf16) ----------------
__global__ __launch_bounds__(256) void gemm2_kernel(const unsigned short* __restrict__ h,
                                                    const unsigned short* __restrict__ w2T,
                                                    const float* __restrict__ b2,
                                                    const int* __restrict__ tileExpert,
                                                    const int* __restrict__ tileRowBase,
                                                    unsigned short* __restrict__ y) {
  int tileId = blockIdx.x;
  int e = tileExpert[tileId];
  if (e < 0) return;
  int rowBase = tileRowBase[tileId];
  int n0 = blockIdx.y * 128;
  __shared__ __align__(16) unsigned short sm[128 * 64 * 2];
  unsigned short* sA = sm;
  unsigned short* sB = sm + 128 * 64;
  int tid = threadIdx.x, lane = tid & 63, wv = tid >> 6;
  int srow = tid >> 3;
  int scolSw = (((tid & 7) ^ ((tid >> 3) & 7)) * 8);
  const unsigned short* Bmat = w2T + (size_t)e * DEXP * DEXP;
  int wm = ((tid >> 6) & 1) * 64, wn = (tid >> 7) * 64;
  int rsel = lane & 15, q = lane >> 4;
  int rk = rsel & 7;
  f32x4 acc[4][4] = {};
  for (int kk = 0; kk < DEXP; kk += 64) {
    #pragma unroll
    for (int i = 0; i < 4; ++i) {
      int abase = __builtin_amdgcn_readfirstlane((wv * 8 + i * 32) * 128);
      async16(h + (size_t)(rowBase + srow + i * 32) * 1024 + kk + scolSw, (char*)sm + abase);
      async16(Bmat + (size_t)(n0 + srow + i * 32) * 1024 + kk + scolSw,
              (char*)sm + abase + 16384);
    }
    __syncthreads();
    #pragma unroll
    for (int ks2 = 0; ks2 < 2; ++ks2) {
      int co = ((ks2 * 4 + q) ^ rk) * 8;
      bf16x8_t af[4], bfr[4];
      #pragma unroll
      for (int mi = 0; mi < 4; ++mi)
        af[mi] = *(const bf16x8_t*)&sA[(wm + mi * 16 + rsel) * 64 + co];
      #pragma unroll
      for (int ni = 0; ni < 4; ++ni)
        bfr[ni] = *(const bf16x8_t*)&sB[(wn + ni * 16 + rsel) * 64 + co];
      #pragma unroll
      for (int mi = 0; mi < 4; ++mi)
        #pragma unroll
        for (int ni = 0; ni < 4; ++ni)
          acc[mi][ni] = __builtin_amdgcn_mfma_f32_16x16x32_bf16(af[mi], bfr[ni], acc[mi][ni], 0, 0, 0);
    }
    __syncthreads();
  }
  float b2v[4];
  int quad = lane >> 4;
  #pragma unroll
  for (int ni = 0; ni < 4; ++ni) b2v[ni] = b2[e * 1024 + n0 + wn + ni * 16 + rsel];
  #pragma unroll
  for (int mi = 0; mi < 4; ++mi)
    #pragma unroll
    for (int ni = 0; ni < 4; ++ni)
      #pragma unroll
      for (int r = 0; r < 4; ++r) {
        int m = wm + mi * 16 + quad * 4 + r;
        int n = wn + ni * 16 + rsel;
        sm[m * 128 + n] = f2bf(acc[mi][ni][r] + b2v[ni]);
      }
  __syncthreads();
  #pragma unroll
  for (int i = 0; i < 8; ++i) {
    int idx = i * 2048 + tid * 8;
    int m = idx >> 7, c = idx & 127;
    int g = rowBase + m;
    *(uint4*)(y + (size_t)g * 1024 + n0 + c) = *(const uint4*)&sm[idx];
  }
}

// ---------------- combine: out[t] = w0*y[r0] + w1*y[r1] ----------------
__global__ __launch_bounds__(256) void combine_kernel(const unsigned short* __restrict__ y,
                                                      const int* __restrict__ topRow,
                                                      const float* __restrict__ topW,
                                                      float* __restrict__ out) {
  int tid = threadIdx.x;
  int wv = tid >> 6, lane = tid & 63;
  int t = blockIdx.x * 4 + wv;
  int r0 = topRow[t * 2 + 0], r1 = topRow[t * 2 + 1];
  float w0 = topW[t * 2 + 0], w1 = topW[t * 2 + 1];
  const unsigned short* p0 = y + (size_t)r0 * 1024 + lane * 16;
  const unsigned short* p1 = y + (size_t)r1 * 1024 + lane * 16;
  float* op = out + (size_t)t * 1024 + lane * 16;
  #pragma unroll
  for (int hh = 0; hh < 2; ++hh) {
    union { uint4 v; unsigned short s[8]; } a, b;
    a.v = *(const uint4*)(p0 + hh * 8);
    b.v = *(const uint4*)(p1 + hh * 8);
    float o[8];
    #pragma unroll
    for (int j = 0; j < 8; ++j)
      o[j] = w0 * bf2f(a.s[j]) + w1 * bf2f(b.s[j]);
    *(float4*)(op + hh * 8) = *(float4*)&o[0];
    *(float4*)(op + hh * 8 + 4) = *(float4*)&o[4];
  }
}

extern "C" void kernel_launch(void* const* d_in, const int* in_sizes, int n_in,
                              void* d_out, int out_size, void* d_ws, size_t ws_size,
                              hipStream_t stream) {
  const float* x  = (const float*)d_in[0];
  const float* gw = (const float*)d_in[1];
  const float* w1 = (const float*)d_in[2];
  const float* b1 = (const float*)d_in[3];
  const float* w2 = (const float*)d_in[4];
  const float* b2 = (const float*)d_in[5];
  float* out = (float*)d_out;

  char* ws = (char*)d_ws;
  int* tileExpert  = (int*)ws;                            // 136
  int* tileRowBase = tileExpert + MAXTILES;               // 136
  int* topE        = tileRowBase + MAXTILES;              // 16384
  int* topRow      = topE + 16384;                        // 16384
  float* topW      = (float*)(topRow + 16384);            // 16384
  int* rowTok      = (int*)(ws + (256 << 10));            // 17408 (16B aligned)
  unsigned short* xbf  = (unsigned short*)(ws + (512 << 10));
  unsigned short* w1T  = xbf + (size_t)NTOK * DIN;
  unsigned short* w2T  = w1T + (size_t)NEXP * DIN * DEXP;
  unsigned short* hbuf = w2T + (size_t)NEXP * DEXP * DEXP;
  unsigned short* ybuf = hbuf + (size_t)MAXROWS * DEXP;

  prep_kernel<<<4096 + 2048 + 17, 256, 0, stream>>>(x, gw, w1, w2, xbf, w1T, w2T,
                                                    out + (size_t)NTOK * DEXP,
                                                    topE, topW, rowTok);
  slot_kernel<<<1, 1024, 0, stream>>>(topE, topRow, rowTok, tileExpert, tileRowBase);
  gemm1_kernel<<<dim3(MAXTILES, 8), 256, 0, stream>>>(xbf, w1T, b1, tileExpert, tileRowBase,
                                                      rowTok, hbuf);
  gemm2_kernel<<<dim3(MAXTILES, 8), 256, 0, stream>>>(hbuf, w2T, b2, tileExpert, tileRowBase,
                                                      ybuf);
  combine_kernel<<<NTOK / 4, 256, 0, stream>>>(ybuf, topRow, topW, out);
}